// Round 7
// baseline (1462.118 us; speedup 1.0000x reference)
//
#include <hip/hip_runtime.h>

// GaussianSoftmax: out[b,n,m] = softmax_m( exp( exp(-max(||x_n-x_m||^2,0)/sigma) ) )
// X: [8, 4096, 16] fp32, sigma: [1], out: [8, 4096, 4096] fp32 (512 MiB).
// R7: SINGLE pass, e kept in 32 VGPRs (no 64KiB LDS, no second compute pass).
// Spill-proofing (R3's failure mode): q/sqn/nis pinned to SGPRs via
// readfirstlane (R6-proven), sqm precomputed by pack kernel, live VGPRs ~85
// under the 128 cap from __launch_bounds__(512,4) -> 2 blocks/CU so one
// block's store phase overlaps the other's compute. Output written once,
// coalesced float4, straight from registers.

constexpr int Bn  = 8;
constexpr int N   = 4096;
constexpr int F   = 16;
constexpr int TN  = 4;       // rows per block
constexpr int BLK = 512;     // 8 waves/block
constexpr int WPB = BLK / 64;
constexpr int GROUPS = (N / 4) / BLK;   // 2 float4-column groups per thread

__global__ __launch_bounds__(256)
void pack_kernel(const float* __restrict__ X, float* __restrict__ Xt,
                 float* __restrict__ sqm) {
    const int b = blockIdx.y;
    const int m = blockIdx.x * 256 + threadIdx.x;
    const float4* src = (const float4*)(X + ((size_t)b * N + m) * F);
    const float4 v0 = src[0], v1 = src[1], v2 = src[2], v3 = src[3];
    const float x[F] = {v0.x, v0.y, v0.z, v0.w, v1.x, v1.y, v1.z, v1.w,
                        v2.x, v2.y, v2.z, v2.w, v3.x, v3.y, v3.z, v3.w};
    float* dst = Xt + (size_t)b * F * N + m;
    float s = 0.f;
    #pragma unroll
    for (int f = 0; f < F; ++f) {
        dst[(size_t)f * N] = x[f];              // coalesced dwords
        s = fmaf(x[f], x[f], s);
    }
    sqm[(size_t)b * N + m] = s;                 // ||x_m||^2
}

__device__ __forceinline__ float uni(float x) {  // force SGPR residency
    return __int_as_float(__builtin_amdgcn_readfirstlane(__float_as_int(x)));
}

__device__ __forceinline__ float gse(float d, float base, float nis) {
    float sqd = fmaxf(fmaf(-2.0f, d, base), 0.0f);
    return __expf(__expf(sqd * nis));
}

__global__ __launch_bounds__(BLK, 4)   // min 4 waves/EU -> <=128 VGPR, 2 blocks/CU
void gs_single(const float* __restrict__ X, const float* __restrict__ Xt,
               const float* __restrict__ sqm, const float* __restrict__ sigma_p,
               float* __restrict__ out) {
    __shared__ float red[TN][WPB];

    const int tid = threadIdx.x;
    const int b   = blockIdx.y;
    const int n0  = blockIdx.x * TN;
    const float* Xb = X + (size_t)b * N * F;

    // Query rows -> SGPRs (wave-uniform, readfirstlane-pinned; R6-proven).
    float q[TN][F];
    float sqn[TN];
    #pragma unroll
    for (int r = 0; r < TN; ++r) {
        float s = 0.f;
        #pragma unroll
        for (int f = 0; f < F; ++f) {
            const float qq = uni(Xb[(size_t)(n0 + r) * F + f]);
            q[r][f] = qq;
            s = fmaf(qq, qq, s);
        }
        sqn[r] = uni(s);
    }
    const float nis = uni(-1.0f / sigma_p[0]);

    const float4* Xt4  = (const float4*)(Xt + (size_t)b * F * N);
    const float4* sqm4 = (const float4*)(sqm + (size_t)b * N);

    float4 e[GROUPS][TN];                 // 32 VGPRs — the whole tile
    float  sums[TN] = {0.f, 0.f, 0.f, 0.f};

    #pragma unroll
    for (int g = 0; g < GROUPS; ++g) {
        const int c4 = g * BLK + tid;     // float4-column index

        float4 d[TN];
        #pragma unroll
        for (int r = 0; r < TN; ++r) d[r] = make_float4(0.f, 0.f, 0.f, 0.f);

        #pragma unroll
        for (int fb = 0; fb < F / 4; ++fb) {
            float4 v0 = Xt4[(size_t)(fb * 4 + 0) * (N / 4) + c4];
            float4 v1 = Xt4[(size_t)(fb * 4 + 1) * (N / 4) + c4];
            float4 v2 = Xt4[(size_t)(fb * 4 + 2) * (N / 4) + c4];
            float4 v3 = Xt4[(size_t)(fb * 4 + 3) * (N / 4) + c4];

            #pragma unroll
            for (int k = 0; k < 4; ++k) {
                const float4 w = (k == 0) ? v0 : (k == 1) ? v1 : (k == 2) ? v2 : v3;
                #pragma unroll
                for (int r = 0; r < TN; ++r) {
                    const float qf = q[r][fb * 4 + k];   // SGPR operand
                    d[r].x = fmaf(qf, w.x, d[r].x);
                    d[r].y = fmaf(qf, w.y, d[r].y);
                    d[r].z = fmaf(qf, w.z, d[r].z);
                    d[r].w = fmaf(qf, w.w, d[r].w);
                }
            }
        }

        const float4 sm = sqm4[c4];       // ||x_m||^2 for these 4 columns

        #pragma unroll
        for (int r = 0; r < TN; ++r) {
            float4 ee;
            ee.x = gse(d[r].x, sqn[r] + sm.x, nis);
            ee.y = gse(d[r].y, sqn[r] + sm.y, nis);
            ee.z = gse(d[r].z, sqn[r] + sm.z, nis);
            ee.w = gse(d[r].w, sqn[r] + sm.w, nis);
            e[g][r] = ee;
            sums[r] += (ee.x + ee.y) + (ee.z + ee.w);
        }
    }

    // Row sums: wave shuffle reduce, then cross-wave via tiny LDS.
    #pragma unroll
    for (int r = 0; r < TN; ++r) {
        float s = sums[r];
        #pragma unroll
        for (int off = 32; off > 0; off >>= 1) s += __shfl_down(s, off, 64);
        if ((tid & 63) == 0) red[r][tid >> 6] = s;
    }
    __syncthreads();

    float inv[TN];
    #pragma unroll
    for (int r = 0; r < TN; ++r) {
        float t = 0.f;
        #pragma unroll
        for (int w = 0; w < WPB; ++w) t += red[r][w];
        inv[r] = 1.0f / t;
    }

    // Store straight from registers; output written exactly once, coalesced.
    float* outb = out + ((size_t)b * N + n0) * (size_t)N;
    #pragma unroll
    for (int g = 0; g < GROUPS; ++g) {
        const int c4 = g * BLK + tid;
        #pragma unroll
        for (int r = 0; r < TN; ++r) {
            float4 v = e[g][r];
            v.x *= inv[r]; v.y *= inv[r]; v.z *= inv[r]; v.w *= inv[r];
            ((float4*)(outb + (size_t)r * N))[c4] = v;
        }
    }
}

extern "C" void kernel_launch(void* const* d_in, const int* in_sizes, int n_in,
                              void* d_out, int out_size, void* d_ws, size_t ws_size,
                              hipStream_t stream) {
    const float* X     = (const float*)d_in[0];
    const float* sigma = (const float*)d_in[1];
    float* out         = (float*)d_out;
    float* Xt          = (float*)d_ws;                        // 2 MiB
    float* sqm         = (float*)d_ws + (size_t)Bn * F * N;   // +128 KiB

    pack_kernel<<<dim3(N / 256, Bn), 256, 0, stream>>>(X, Xt, sqm);
    gs_single<<<dim3(N / TN, Bn), BLK, 0, stream>>>(X, Xt, sqm, sigma, out);
}

// Round 8
// 672.812 us; speedup vs baseline: 2.1731x; 2.1731x over previous
//
#include <hip/hip_runtime.h>

// GaussianSoftmax: out[b,n,m] = softmax_m( exp( exp(-max(||x_n-x_m||^2,0)/sigma) ) )
// X: [8, 4096, 16] fp32, sigma: [1], out: [8, 4096, 4096] fp32 (512 MiB).
// R8: single pass, BLK=1024 so each thread owns EXACTLY ONE float4-column
// (c4 = tid) -> e overwrites d in place, no e-array, no 64KiB LDS.
// Live VGPRs ~45 by construction: fits the allocator's stubborn 64-VGPR
// target (R3/R5/R7 all spilled when live >64; hints don't move it).
// q/sqn/nis pinned to SGPRs via readfirstlane (R6-proven). Packed f-major
// Xt (R2) kills 64B-stride sector fragmentation; sqm precomputed. One
// barrier, then scale+store from registers; output written exactly once.

constexpr int Bn  = 8;
constexpr int N   = 4096;
constexpr int F   = 16;
constexpr int TN  = 4;        // rows per block
constexpr int BLK = 1024;     // 16 waves; one float4-col per thread (N/4 = 1024)
constexpr int WPB = BLK / 64;

__global__ __launch_bounds__(256)
void pack_kernel(const float* __restrict__ X, float* __restrict__ Xt,
                 float* __restrict__ sqm) {
    const int b = blockIdx.y;
    const int m = blockIdx.x * 256 + threadIdx.x;
    const float4* src = (const float4*)(X + ((size_t)b * N + m) * F);
    const float4 v0 = src[0], v1 = src[1], v2 = src[2], v3 = src[3];
    const float x[F] = {v0.x, v0.y, v0.z, v0.w, v1.x, v1.y, v1.z, v1.w,
                        v2.x, v2.y, v2.z, v2.w, v3.x, v3.y, v3.z, v3.w};
    float* dst = Xt + (size_t)b * F * N + m;
    float s = 0.f;
    #pragma unroll
    for (int f = 0; f < F; ++f) {
        dst[(size_t)f * N] = x[f];              // coalesced dwords
        s = fmaf(x[f], x[f], s);
    }
    sqm[(size_t)b * N + m] = s;                 // ||x_m||^2
}

__device__ __forceinline__ float uni(float x) {  // force SGPR residency
    return __int_as_float(__builtin_amdgcn_readfirstlane(__float_as_int(x)));
}

__device__ __forceinline__ float gse(float d, float base, float nis) {
    float sqd = fmaxf(fmaf(-2.0f, d, base), 0.0f);
    return __expf(__expf(sqd * nis));
}

__global__ __launch_bounds__(BLK)
void gs_single(const float* __restrict__ X, const float* __restrict__ Xt,
               const float* __restrict__ sqm, const float* __restrict__ sigma_p,
               float* __restrict__ out) {
    __shared__ float red[TN][WPB];

    const int tid = threadIdx.x;
    const int b   = blockIdx.y;
    const int n0  = blockIdx.x * TN;
    const float* Xb = X + (size_t)b * N * F;

    // Query rows -> SGPRs (wave-uniform, readfirstlane-pinned).
    float q[TN][F];
    float sqn[TN];
    #pragma unroll
    for (int r = 0; r < TN; ++r) {
        float s = 0.f;
        #pragma unroll
        for (int f = 0; f < F; ++f) {
            const float qq = uni(Xb[(size_t)(n0 + r) * F + f]);
            q[r][f] = qq;
            s = fmaf(qq, qq, s);
        }
        sqn[r] = uni(s);
    }
    const float nis = uni(-1.0f / sigma_p[0]);

    const float4* Xt4  = (const float4*)(Xt + (size_t)b * F * N);
    const float4* sqm4 = (const float4*)(sqm + (size_t)b * N);
    const int c4 = tid;                    // this thread's float4-column

    float4 d[TN];
    #pragma unroll
    for (int r = 0; r < TN; ++r) d[r] = make_float4(0.f, 0.f, 0.f, 0.f);

    #pragma unroll
    for (int fb = 0; fb < F / 4; ++fb) {
        float4 v0 = Xt4[(size_t)(fb * 4 + 0) * (N / 4) + c4];
        float4 v1 = Xt4[(size_t)(fb * 4 + 1) * (N / 4) + c4];
        float4 v2 = Xt4[(size_t)(fb * 4 + 2) * (N / 4) + c4];
        float4 v3 = Xt4[(size_t)(fb * 4 + 3) * (N / 4) + c4];

        #pragma unroll
        for (int k = 0; k < 4; ++k) {
            const float4 w = (k == 0) ? v0 : (k == 1) ? v1 : (k == 2) ? v2 : v3;
            #pragma unroll
            for (int r = 0; r < TN; ++r) {
                const float qf = q[r][fb * 4 + k];   // SGPR operand
                d[r].x = fmaf(qf, w.x, d[r].x);
                d[r].y = fmaf(qf, w.y, d[r].y);
                d[r].z = fmaf(qf, w.z, d[r].z);
                d[r].w = fmaf(qf, w.w, d[r].w);
            }
        }
    }

    const float4 sm = sqm4[c4];            // ||x_m||^2 for these 4 columns

    float sums[TN];
    #pragma unroll
    for (int r = 0; r < TN; ++r) {         // e overwrites d in place
        d[r].x = gse(d[r].x, sqn[r] + sm.x, nis);
        d[r].y = gse(d[r].y, sqn[r] + sm.y, nis);
        d[r].z = gse(d[r].z, sqn[r] + sm.z, nis);
        d[r].w = gse(d[r].w, sqn[r] + sm.w, nis);
        sums[r] = (d[r].x + d[r].y) + (d[r].z + d[r].w);
    }

    // Row sums: wave shuffle reduce, then cross-wave via tiny LDS.
    #pragma unroll
    for (int r = 0; r < TN; ++r) {
        float s = sums[r];
        #pragma unroll
        for (int off = 32; off > 0; off >>= 1) s += __shfl_down(s, off, 64);
        if ((tid & 63) == 0) red[r][tid >> 6] = s;
    }
    __syncthreads();

    float inv[TN];
    #pragma unroll
    for (int r = 0; r < TN; ++r) {
        float t = 0.f;
        #pragma unroll
        for (int w = 0; w < WPB; ++w) t += red[r][w];   // broadcast reads
        inv[r] = 1.0f / t;
    }

    // Scale + store straight from registers; output written exactly once.
    float* outb = out + ((size_t)b * N + n0) * (size_t)N;
    #pragma unroll
    for (int r = 0; r < TN; ++r) {
        float4 v = d[r];
        v.x *= inv[r]; v.y *= inv[r]; v.z *= inv[r]; v.w *= inv[r];
        ((float4*)(outb + (size_t)r * N))[c4] = v;
    }
}

extern "C" void kernel_launch(void* const* d_in, const int* in_sizes, int n_in,
                              void* d_out, int out_size, void* d_ws, size_t ws_size,
                              hipStream_t stream) {
    const float* X     = (const float*)d_in[0];
    const float* sigma = (const float*)d_in[1];
    float* out         = (float*)d_out;
    float* Xt          = (float*)d_ws;                        // 2 MiB
    float* sqm         = (float*)d_ws + (size_t)Bn * F * N;   // +128 KiB

    pack_kernel<<<dim3(N / 256, Bn), 256, 0, stream>>>(X, Xt, sqm);
    gs_single<<<dim3(N / TN, Bn), BLK, 0, stream>>>(X, Xt, sqm, sigma, out);
}

// Round 11
// 560.239 us; speedup vs baseline: 2.6098x; 1.2009x over previous
//
#include <hip/hip_runtime.h>

// GaussianSoftmax: out[b,n,m] = softmax_m( exp( exp(-max(||x_n-x_m||^2,0)/sigma) ) )
// X: [8, 4096, 16] fp32, sigma: [1], out: [8, 4096, 4096] fp32 (512 MiB).
// R11 = R9 resubmitted verbatim (R9/R10 hit GPUAcquisitionTimeout; never ran).
// R9 = R4 (best: single pass, e staged in LDS, packed f-major Xt) with:
//  - e stored as bf16 -> LDS 32 KiB -> 4 blocks/CU (was 2): cross-block
//    phase overlap (store of one block vs compute of another), half LDS traffic.
//    Precision: e in (1,2.72], bf16 RNE rel err <=0.2% -> out err <=1.3e-6,
//    10x under the 1.33e-5 threshold.
//  - q: 16 vector float4 loads + readfirstlane per component (one latency
//    round-trip with full ILP; R8's 64 serialized broadcast loads were ~1.5x
//    the useful work). q/sqn/nis SGPR-pinned; VGPR live ~55 < 64 (no spill
//    at the allocator's stubborn 64-VGPR target seen in R3/R5/R7).
//  - sqm precomputed in pack kernel (R8-proven); nontemporal out stores.

typedef float v4f __attribute__((ext_vector_type(4)));

constexpr int Bn  = 8;
constexpr int N   = 4096;
constexpr int F   = 16;
constexpr int TN  = 4;       // rows per block
constexpr int BLK = 512;     // 8 waves/block; 4 blocks/CU (LDS 32K) = 32 waves/CU
constexpr int WPB = BLK / 64;
constexpr int GROUPS = (N / 4) / BLK;   // 2 float4-column groups per thread

__global__ __launch_bounds__(256)
void pack_kernel(const float* __restrict__ X, float* __restrict__ Xt,
                 float* __restrict__ sqm) {
    const int b = blockIdx.y;
    const int m = blockIdx.x * 256 + threadIdx.x;
    const float4* src = (const float4*)(X + ((size_t)b * N + m) * F);
    const float4 v0 = src[0], v1 = src[1], v2 = src[2], v3 = src[3];
    const float x[F] = {v0.x, v0.y, v0.z, v0.w, v1.x, v1.y, v1.z, v1.w,
                        v2.x, v2.y, v2.z, v2.w, v3.x, v3.y, v3.z, v3.w};
    float* dst = Xt + (size_t)b * F * N + m;
    float s = 0.f;
    #pragma unroll
    for (int f = 0; f < F; ++f) {
        dst[(size_t)f * N] = x[f];              // coalesced dwords
        s = fmaf(x[f], x[f], s);
    }
    sqm[(size_t)b * N + m] = s;                 // ||x_m||^2
}

__device__ __forceinline__ float uni(float x) {  // force SGPR residency
    return __int_as_float(__builtin_amdgcn_readfirstlane(__float_as_int(x)));
}

__device__ __forceinline__ float gse(float d, float base, float nis) {
    float sqd = fmaxf(fmaf(-2.0f, d, base), 0.0f);
    return __expf(__expf(sqd * nis));
}

__device__ __forceinline__ unsigned short f2bf(float x) {   // RNE, no NaN in range
    unsigned int u = __float_as_uint(x);
    unsigned int r = (u + 0x7FFFu + ((u >> 16) & 1u)) >> 16;
    return (unsigned short)r;
}
__device__ __forceinline__ float bf2f(unsigned short h) {
    return __uint_as_float(((unsigned int)h) << 16);
}

__global__ __launch_bounds__(BLK)
void gs_single(const float* __restrict__ X, const float* __restrict__ Xt,
               const float* __restrict__ sqm, const float* __restrict__ sigma_p,
               float* __restrict__ out) {
    __shared__ unsigned short lds_e[TN][N];   // 32 KiB (bf16 e)
    __shared__ float red[TN][WPB];

    const int tid = threadIdx.x;
    const int b   = blockIdx.y;
    const int n0  = blockIdx.x * TN;

    // Query rows: 16 vector loads (full ILP, one latency round-trip), then
    // readfirstlane every component -> SGPRs.
    const float4* qbase = (const float4*)(X + ((size_t)b * N + n0) * F);
    float q[TN][F];
    float sqn[TN];
    #pragma unroll
    for (int r = 0; r < TN; ++r) {
        const float4 a0 = qbase[r * 4 + 0];
        const float4 a1 = qbase[r * 4 + 1];
        const float4 a2 = qbase[r * 4 + 2];
        const float4 a3 = qbase[r * 4 + 3];
        q[r][ 0] = uni(a0.x); q[r][ 1] = uni(a0.y); q[r][ 2] = uni(a0.z); q[r][ 3] = uni(a0.w);
        q[r][ 4] = uni(a1.x); q[r][ 5] = uni(a1.y); q[r][ 6] = uni(a1.z); q[r][ 7] = uni(a1.w);
        q[r][ 8] = uni(a2.x); q[r][ 9] = uni(a2.y); q[r][10] = uni(a2.z); q[r][11] = uni(a2.w);
        q[r][12] = uni(a3.x); q[r][13] = uni(a3.y); q[r][14] = uni(a3.z); q[r][15] = uni(a3.w);
        float s = 0.f;
        #pragma unroll
        for (int f = 0; f < F; ++f) s = fmaf(q[r][f], q[r][f], s);
        sqn[r] = uni(s);
    }
    const float nis = uni(-1.0f / sigma_p[0]);

    const float4* Xt4  = (const float4*)(Xt + (size_t)b * F * N);
    const float4* sqm4 = (const float4*)(sqm + (size_t)b * N);

    float sums[TN] = {0.f, 0.f, 0.f, 0.f};

    #pragma unroll
    for (int g = 0; g < GROUPS; ++g) {
        const int c4 = g * BLK + tid;     // float4-column index

        float4 d[TN];
        #pragma unroll
        for (int r = 0; r < TN; ++r) d[r] = make_float4(0.f, 0.f, 0.f, 0.f);

        #pragma unroll
        for (int fb = 0; fb < F / 4; ++fb) {
            float4 v0 = Xt4[(size_t)(fb * 4 + 0) * (N / 4) + c4];
            float4 v1 = Xt4[(size_t)(fb * 4 + 1) * (N / 4) + c4];
            float4 v2 = Xt4[(size_t)(fb * 4 + 2) * (N / 4) + c4];
            float4 v3 = Xt4[(size_t)(fb * 4 + 3) * (N / 4) + c4];

            #pragma unroll
            for (int k = 0; k < 4; ++k) {
                const float4 w = (k == 0) ? v0 : (k == 1) ? v1 : (k == 2) ? v2 : v3;
                #pragma unroll
                for (int r = 0; r < TN; ++r) {
                    const float qf = q[r][fb * 4 + k];   // SGPR operand
                    d[r].x = fmaf(qf, w.x, d[r].x);
                    d[r].y = fmaf(qf, w.y, d[r].y);
                    d[r].z = fmaf(qf, w.z, d[r].z);
                    d[r].w = fmaf(qf, w.w, d[r].w);
                }
            }
        }

        const float4 sm = sqm4[c4];       // ||x_m||^2 for these 4 columns

        #pragma unroll
        for (int r = 0; r < TN; ++r) {
            float ex = gse(d[r].x, sqn[r] + sm.x, nis);
            float ey = gse(d[r].y, sqn[r] + sm.y, nis);
            float ez = gse(d[r].z, sqn[r] + sm.z, nis);
            float ew = gse(d[r].w, sqn[r] + sm.w, nis);
            ushort4 pk;
            pk.x = f2bf(ex); pk.y = f2bf(ey); pk.z = f2bf(ez); pk.w = f2bf(ew);
            *(ushort4*)&lds_e[r][4 * c4] = pk;     // ds_write_b64, 2-way=free
            sums[r] += (ex + ey) + (ez + ew);
        }
    }

    // Row sums: wave shuffle reduce, then cross-wave via tiny LDS.
    #pragma unroll
    for (int r = 0; r < TN; ++r) {
        float s = sums[r];
        #pragma unroll
        for (int off = 32; off > 0; off >>= 1) s += __shfl_down(s, off, 64);
        if ((tid & 63) == 0) red[r][tid >> 6] = s;
    }
    __syncthreads();   // lds_e + red all visible

    float inv[TN];
    #pragma unroll
    for (int r = 0; r < TN; ++r) {
        float t = 0.f;
        #pragma unroll
        for (int w = 0; w < WPB; ++w) t += red[r][w];   // broadcast reads
        inv[r] = 1.0f / t;
    }

    // Store phase: bf16 -> f32, scale, nontemporal coalesced stores (out is
    // write-once / never re-read: keep it out of L2's way).
    float* outb = out + ((size_t)b * N + n0) * (size_t)N;
    #pragma unroll
    for (int r = 0; r < TN; ++r) {
        #pragma unroll
        for (int g = 0; g < GROUPS; ++g) {
            const int c4 = g * BLK + tid;
            ushort4 pk = *(const ushort4*)&lds_e[r][4 * c4];
            v4f v;
            v.x = bf2f(pk.x) * inv[r];
            v.y = bf2f(pk.y) * inv[r];
            v.z = bf2f(pk.z) * inv[r];
            v.w = bf2f(pk.w) * inv[r];
            __builtin_nontemporal_store(v, (v4f*)(outb + (size_t)r * N) + c4);
        }
    }
}

extern "C" void kernel_launch(void* const* d_in, const int* in_sizes, int n_in,
                              void* d_out, int out_size, void* d_ws, size_t ws_size,
                              hipStream_t stream) {
    const float* X     = (const float*)d_in[0];
    const float* sigma = (const float*)d_in[1];
    float* out         = (float*)d_out;
    float* Xt          = (float*)d_ws;                        // 2 MiB
    float* sqm         = (float*)d_ws + (size_t)Bn * F * N;   // +128 KiB

    pack_kernel<<<dim3(N / 256, Bn), 256, 0, stream>>>(X, Xt, sqm);
    gs_single<<<dim3(N / TN, Bn), BLK, 0, stream>>>(X, Xt, sqm, sigma, out);
}